// Round 4
// baseline (375.748 us; speedup 1.0000x reference)
//
#include <hip/hip_runtime.h>

// Problem constants
#define B_ 512
#define L_ 256
#define D_ 1024
#define H_ 16
#define DK_ 64
#define DV_ 64
// TEMP = sqrt(1024) = 32 exactly (folded into Aq in k_aq)

typedef float f32x4 __attribute__((ext_vector_type(4)));
typedef float f32x2 __attribute__((ext_vector_type(2)));
typedef __bf16 bf16x8 __attribute__((ext_vector_type(8)));
typedef __bf16 bf16x2 __attribute__((ext_vector_type(2)));

#define MFMA16(a, b, c) __builtin_amdgcn_mfma_f32_16x16x32_bf16((a), (b), (c), 0, 0, 0)

__device__ inline bf16x8 cvt8(f32x4 a, f32x4 b) {
  bf16x8 r;
  r[0] = (__bf16)a[0]; r[1] = (__bf16)a[1]; r[2] = (__bf16)a[2]; r[3] = (__bf16)a[3];
  r[4] = (__bf16)b[0]; r[5] = (__bf16)b[1]; r[6] = (__bf16)b[2]; r[7] = (__bf16)b[3];
  return r;
}

// ---------------------------------------------------------------------------
// K0: transpose Wk [16][64][1024] -> WkT [16][1024][64] (LDS-tiled, coalesced)
// grid (16 d-tiles, 16 h), block 256.
// ---------------------------------------------------------------------------
__global__ __launch_bounds__(256) void k_wkT(const float* __restrict__ Wk,
                                             float* __restrict__ WkT) {
  __shared__ float t[64][65];
  int h = blockIdx.y, d0 = blockIdx.x * 64;
  int tid = threadIdx.x;
  int lr = tid >> 6;   // 0..3
  int lc = tid & 63;   // 0..63
  const float* src = Wk + (size_t)h * DK_ * D_;
#pragma unroll
  for (int r = 0; r < 16; ++r) {
    int kk = r * 4 + lr;
    t[kk][lc] = src[(size_t)kk * D_ + d0 + lc];
  }
  __syncthreads();
  float* dst = WkT + (size_t)h * D_ * DK_;
#pragma unroll
  for (int r = 0; r < 16; ++r) {
    int d = r * 4 + lr;
    dst[(size_t)(d0 + d) * DK_ + lc] = t[lc][d];
  }
}

// ---------------------------------------------------------------------------
// K1: hq[b, h*DK+kk] = sum_d q[b,d] * Wq[h*DK+kk, d]   (Wq viewed [1024][1024])
// ---------------------------------------------------------------------------
__global__ __launch_bounds__(256) void k_hq(const float* __restrict__ q,
                                            const float* __restrict__ Wq,
                                            __bf16* __restrict__ hq) {
  int tid = threadIdx.x, lane = tid & 63, wid = tid >> 6;
  int r16 = lane & 15, g = lane >> 4;
  int n0 = (blockIdx.x * 4 + wid) * 16;
  int m0 = blockIdx.y * 16;
  const float* arow = q  + (size_t)(m0 + r16) * D_;
  const float* brow = Wq + (size_t)(n0 + r16) * D_;
  f32x4 acc = {0.f, 0.f, 0.f, 0.f};
  for (int ks = 0; ks < D_ / 32; ++ks) {
    int k0 = ks * 32 + g * 8;
    f32x4 a0 = *(const f32x4*)(arow + k0);
    f32x4 a1 = *(const f32x4*)(arow + k0 + 4);
    f32x4 b0 = *(const f32x4*)(brow + k0);
    f32x4 b1 = *(const f32x4*)(brow + k0 + 4);
    acc = MFMA16(cvt8(a0, a1), cvt8(b0, b1), acc);
  }
#pragma unroll
  for (int r = 0; r < 4; ++r) {
    int m = m0 + g * 4 + r;
    hq[(size_t)m * (H_ * DK_) + n0 + r16] = (__bf16)acc[r];
  }
}

// ---------------------------------------------------------------------------
// K2: Aq[b, h, d] = (1/32) * sum_kk hq[b, h*64+kk] * WkT[h, d, kk]
// B-fragments now 16B contiguous vector loads from WkT.
// ---------------------------------------------------------------------------
__global__ __launch_bounds__(256) void k_aq(const __bf16* __restrict__ hq,
                                            const float* __restrict__ WkT,
                                            __bf16* __restrict__ Aq) {
  int tid = threadIdx.x, lane = tid & 63, wid = tid >> 6;
  int r16 = lane & 15, g = lane >> 4;
  int h = blockIdx.z;
  int n0 = (blockIdx.x * 4 + wid) * 16;
  int m0 = blockIdx.y * 16;
  const __bf16* arow = hq + (size_t)(m0 + r16) * (H_ * DK_) + h * DK_;
  const float* brow = WkT + ((size_t)h * D_ + n0 + r16) * DK_;
  f32x4 acc = {0.f, 0.f, 0.f, 0.f};
#pragma unroll
  for (int ks = 0; ks < 2; ++ks) {
    int k0 = ks * 32 + g * 8;
    bf16x8 a = *(const bf16x8*)(arow + k0);
    f32x4 b0 = *(const f32x4*)(brow + k0);
    f32x4 b1 = *(const f32x4*)(brow + k0 + 4);
    acc = MFMA16(a, cvt8(b0, b1), acc);
  }
#pragma unroll
  for (int r = 0; r < 4; ++r) {
    int m = m0 + g * 4 + r;
    Aq[(size_t)m * (H_ * D_) + (size_t)h * D_ + n0 + r16] = (__bf16)(acc[r] * 0.03125f);
  }
}

// ---------------------------------------------------------------------------
// K3a: scores[b, h, l] = Aq[b,h,:] . k[b,l,:]   (temp already folded)
// grid (4, 512): x = l-quarter (64 rows), y = b. block 256 (4 waves).
// ---------------------------------------------------------------------------
__global__ __launch_bounds__(256) void k_score(const float* __restrict__ kg,
                                               const __bf16* __restrict__ Aq,
                                               float* __restrict__ sc) {
  int tid = threadIdx.x, lane = tid & 63, wv = tid >> 6;
  int r16 = lane & 15, g = lane >> 4;
  int b = blockIdx.y;
  int l0 = blockIdx.x * 64 + wv * 16;
  const __bf16* AqB = Aq + (size_t)b * H_ * D_;
  const float*  kR  = kg + ((size_t)b * L_ + l0 + r16) * D_;
  f32x4 acc = {0.f, 0.f, 0.f, 0.f};
#pragma unroll 4
  for (int ks = 0; ks < D_ / 32; ++ks) {
    int k0 = ks * 32 + g * 8;
    bf16x8 a = *(const bf16x8*)(AqB + (size_t)r16 * D_ + k0);
    f32x4 b0 = *(const f32x4*)(kR + k0);
    f32x4 b1 = *(const f32x4*)(kR + k0 + 4);
    acc = MFMA16(a, cvt8(b0, b1), acc);
  }
#pragma unroll
  for (int r = 0; r < 4; ++r) {
    int h = g * 4 + r;
    sc[((size_t)b * H_ + h) * L_ + l0 + r16] = acc[r];
  }
}

// ---------------------------------------------------------------------------
// K3b: softmax (fused prologue) + cv[b,h,d] = sum_l w[h,l] * v[b,l,d]
// grid (4, 512): x = d-quarter (256 cols), y = b. block 256; 1 col/thread.
// 2048 blocks * 4 waves = 8192 waves -> 100% occupancy target.
// ---------------------------------------------------------------------------
#define WPAD 17
__global__ __launch_bounds__(256) void k_cv(const float* __restrict__ vg,
                                            const float* __restrict__ sc,
                                            __bf16* __restrict__ cv) {
  __shared__ float wT[L_][WPAD];  // transposed weights wT[l][h], 17.4KB

  int tid = threadIdx.x, lane = tid & 63, wv = tid >> 6;
  int b = blockIdx.y;

  // ---- softmax: wave wv handles head rows wv*4 .. wv*4+3
  const float* scB = sc + (size_t)b * H_ * L_;
#pragma unroll
  for (int rr = 0; rr < 4; ++rr) {
    int row = wv * 4 + rr;
    const float* srow = scB + (size_t)row * L_;
    float x0 = srow[lane], x1 = srow[lane + 64];
    float x2 = srow[lane + 128], x3 = srow[lane + 192];
    float m = fmaxf(fmaxf(x0, x1), fmaxf(x2, x3));
#pragma unroll
    for (int off = 32; off; off >>= 1) m = fmaxf(m, __shfl_xor(m, off));
    float e0 = __expf(x0 - m), e1 = __expf(x1 - m);
    float e2 = __expf(x2 - m), e3 = __expf(x3 - m);
    float s = e0 + e1 + e2 + e3;
#pragma unroll
    for (int off = 32; off; off >>= 1) s += __shfl_xor(s, off);
    float inv = 1.0f / s;
    wT[lane]      [row] = e0 * inv;
    wT[lane + 64] [row] = e1 * inv;
    wT[lane + 128][row] = e2 * inv;
    wT[lane + 192][row] = e3 * inv;
  }
  __syncthreads();

  // ---- main: stream v coalesced (1 f32/thread/row), w broadcast from LDS.
  int c0 = blockIdx.x * 256 + tid;
  const float* vC = vg + (size_t)b * L_ * D_ + c0;
  float acc[16];
#pragma unroll
  for (int h = 0; h < 16; ++h) acc[h] = 0.f;

#pragma unroll 2
  for (int l = 0; l < L_; ++l) {
    float v1 = vC[(size_t)l * D_];
    f32x4 w0 = *(const f32x4*)(&wT[l][0]);   // broadcast reads
    f32x4 w1 = *(const f32x4*)(&wT[l][4]);
    f32x4 w2 = *(const f32x4*)(&wT[l][8]);
    f32x4 w3 = *(const f32x4*)(&wT[l][12]);
#pragma unroll
    for (int j = 0; j < 4; ++j) {
      acc[j]      += w0[j] * v1;
      acc[4 + j]  += w1[j] * v1;
      acc[8 + j]  += w2[j] * v1;
      acc[12 + j] += w3[j] * v1;
    }
  }
#pragma unroll
  for (int h = 0; h < 16; ++h)
    cv[((size_t)b * H_ + h) * D_ + c0] = (__bf16)acc[h];
}

// ---------------------------------------------------------------------------
// K4: ctx[b, h*64+vv] = sum_d cv[b,h,d] * Wv[h,vv,d]
// ---------------------------------------------------------------------------
__global__ __launch_bounds__(256) void k_ctx(const __bf16* __restrict__ cv,
                                             const float* __restrict__ Wv,
                                             __bf16* __restrict__ ctx) {
  int tid = threadIdx.x, lane = tid & 63, wid = tid >> 6;
  int r16 = lane & 15, g = lane >> 4;
  int h = blockIdx.z, m0 = blockIdx.y * 16, n0 = wid * 16;
  const __bf16* arow = cv + (size_t)(m0 + r16) * (H_ * D_) + (size_t)h * D_;
  const float* brow = Wv + (size_t)h * DV_ * D_ + (size_t)(n0 + r16) * D_;
  f32x4 acc = {0.f, 0.f, 0.f, 0.f};
  for (int ks = 0; ks < D_ / 32; ++ks) {
    int k0 = ks * 32 + g * 8;
    bf16x8 a = *(const bf16x8*)(arow + k0);
    f32x4 b0 = *(const f32x4*)(brow + k0);
    f32x4 b1 = *(const f32x4*)(brow + k0 + 4);
    acc = MFMA16(a, cvt8(b0, b1), acc);
  }
#pragma unroll
  for (int r = 0; r < 4; ++r) {
    int m = m0 + g * 4 + r;
    ctx[(size_t)m * (H_ * DV_) + h * DV_ + n0 + r16] = (__bf16)acc[r];
  }
}

// ---------------------------------------------------------------------------
// K5: outp[b,d] = sum_j ctx[b,j] * Wp[d,j] + q[b,d]
// ---------------------------------------------------------------------------
__global__ __launch_bounds__(256) void k_out(const __bf16* __restrict__ ctx,
                                             const float* __restrict__ Wp,
                                             const float* __restrict__ q,
                                             float* __restrict__ outp) {
  int tid = threadIdx.x, lane = tid & 63, wid = tid >> 6;
  int r16 = lane & 15, g = lane >> 4;
  int n0 = (blockIdx.x * 4 + wid) * 16;
  int m0 = blockIdx.y * 16;
  const __bf16* arow = ctx + (size_t)(m0 + r16) * D_;
  const float* brow = Wp + (size_t)(n0 + r16) * D_;
  f32x4 acc = {0.f, 0.f, 0.f, 0.f};
  for (int ks = 0; ks < D_ / 32; ++ks) {
    int k0 = ks * 32 + g * 8;
    bf16x8 a = *(const bf16x8*)(arow + k0);
    f32x4 b0 = *(const f32x4*)(brow + k0);
    f32x4 b1 = *(const f32x4*)(brow + k0 + 4);
    acc = MFMA16(a, cvt8(b0, b1), acc);
  }
#pragma unroll
  for (int r = 0; r < 4; ++r) {
    int m = m0 + g * 4 + r;
    outp[(size_t)m * D_ + n0 + r16] = acc[r] + q[(size_t)m * D_ + n0 + r16];
  }
}

// ---------------------------------------------------------------------------
// K6: LayerNorm, unbiased std (D-1), eps=1 added to STD.
// ---------------------------------------------------------------------------
__global__ __launch_bounds__(256) void k_ln(const float* __restrict__ xin,
                                            const float* __restrict__ scale,
                                            const float* __restrict__ offs,
                                            float* __restrict__ out) {
  __shared__ float red[4];
  int b = blockIdx.x, tid = threadIdx.x;
  const float* row = xin + (size_t)b * D_;
  f32x4 x = *(const f32x4*)(row + tid * 4);
  float s = x[0] + x[1] + x[2] + x[3];
#pragma unroll
  for (int off = 32; off; off >>= 1) s += __shfl_xor(s, off);
  if ((tid & 63) == 0) red[tid >> 6] = s;
  __syncthreads();
  float mean = (red[0] + red[1] + red[2] + red[3]) * (1.0f / D_);
  __syncthreads();  // before reusing red
  float vs = 0.f;
#pragma unroll
  for (int j = 0; j < 4; ++j) { float d = x[j] - mean; vs += d * d; }
#pragma unroll
  for (int off = 32; off; off >>= 1) vs += __shfl_xor(vs, off);
  if ((tid & 63) == 0) red[tid >> 6] = vs;
  __syncthreads();
  float var = (red[0] + red[1] + red[2] + red[3]) * (1.0f / (D_ - 1));
  float inv = 1.0f / (sqrtf(var) + 1.0f);
  f32x4 sc = *(const f32x4*)(scale + tid * 4);
  f32x4 of = *(const f32x4*)(offs + tid * 4);
  f32x4 o;
#pragma unroll
  for (int j = 0; j < 4; ++j) o[j] = sc[j] * (x[j] - mean) * inv + of[j];
  *(f32x4*)(out + (size_t)b * D_ + tid * 4) = o;
}

// ---------------------------------------------------------------------------
extern "C" void kernel_launch(void* const* d_in, const int* in_sizes, int n_in,
                              void* d_out, int out_size, void* d_ws, size_t ws_size,
                              hipStream_t stream) {
  const float* q     = (const float*)d_in[0];
  const float* k     = (const float*)d_in[1];
  const float* v     = (const float*)d_in[2];
  const float* Wq    = (const float*)d_in[3];
  const float* Wk    = (const float*)d_in[4];
  const float* Wv    = (const float*)d_in[5];
  const float* Wp    = (const float*)d_in[6];
  const float* scale = (const float*)d_in[7];
  const float* offs  = (const float*)d_in[8];
  float* out = (float*)d_out;

  // Workspace layout:
  char* ws = (char*)d_ws;
  __bf16* hq   = (__bf16*)(ws);                          // 1 MB
  __bf16* Aq   = (__bf16*)(ws + (size_t)1  * (1 << 20)); // 16 MB
  float*  scr  = (float*) (ws + (size_t)17 * (1 << 20)); // 8 MB  (raw scores)
  __bf16* cv   = (__bf16*)(ws + (size_t)25 * (1 << 20)); // 16 MB
  __bf16* ctx  = (__bf16*)(ws + (size_t)41 * (1 << 20)); // 1 MB
  float*  outp = (float*) (ws + (size_t)42 * (1 << 20)); // 2 MB
  float*  WkT  = (float*) (ws + (size_t)44 * (1 << 20)); // 4 MB

  k_wkT  <<<dim3(16, 16),     256, 0, stream>>>(Wk, WkT);
  k_hq   <<<dim3(16, 32),     256, 0, stream>>>(q, Wq, hq);
  k_aq   <<<dim3(16, 32, 16), 256, 0, stream>>>(hq, WkT, Aq);
  k_score<<<dim3(4, 512),     256, 0, stream>>>(k, Aq, scr);
  k_cv   <<<dim3(4, 512),     256, 0, stream>>>(v, scr, cv);
  k_ctx  <<<dim3(1, 32, 16),  256, 0, stream>>>(cv, Wv, ctx);
  k_out  <<<dim3(16, 32),     256, 0, stream>>>(ctx, Wp, q, outp);
  k_ln   <<<dim3(512),        256, 0, stream>>>(outp, scale, offs, out);
}

// Round 5
// 312.873 us; speedup vs baseline: 1.2010x; 1.2010x over previous
//
#include <hip/hip_runtime.h>

// Problem constants
#define B_ 512
#define L_ 256
#define D_ 1024
#define H_ 16
#define DK_ 64
#define DV_ 64
// TEMP = sqrt(1024) = 32 exactly (folded into Aq in k_aq)

typedef float f32x4 __attribute__((ext_vector_type(4)));
typedef float f32x2 __attribute__((ext_vector_type(2)));
typedef __bf16 bf16x8 __attribute__((ext_vector_type(8)));
typedef __bf16 bf16x2 __attribute__((ext_vector_type(2)));

#define MFMA16(a, b, c) __builtin_amdgcn_mfma_f32_16x16x32_bf16((a), (b), (c), 0, 0, 0)

__device__ inline bf16x8 cvt8(f32x4 a, f32x4 b) {
  bf16x8 r;
  r[0] = (__bf16)a[0]; r[1] = (__bf16)a[1]; r[2] = (__bf16)a[2]; r[3] = (__bf16)a[3];
  r[4] = (__bf16)b[0]; r[5] = (__bf16)b[1]; r[6] = (__bf16)b[2]; r[7] = (__bf16)b[3];
  return r;
}

// ---------------------------------------------------------------------------
// K1: hq[b, h*DK+kk] = sum_d q[b,d] * Wq[h*DK+kk, d]   (Wq viewed [1024][1024])
// ---------------------------------------------------------------------------
__global__ __launch_bounds__(256) void k_hq(const float* __restrict__ q,
                                            const float* __restrict__ Wq,
                                            __bf16* __restrict__ hq) {
  int tid = threadIdx.x, lane = tid & 63, wid = tid >> 6;
  int r16 = lane & 15, g = lane >> 4;
  int n0 = (blockIdx.x * 4 + wid) * 16;
  int m0 = blockIdx.y * 16;
  const float* arow = q  + (size_t)(m0 + r16) * D_;
  const float* brow = Wq + (size_t)(n0 + r16) * D_;
  f32x4 acc = {0.f, 0.f, 0.f, 0.f};
  for (int ks = 0; ks < D_ / 32; ++ks) {
    int k0 = ks * 32 + g * 8;
    f32x4 a0 = *(const f32x4*)(arow + k0);
    f32x4 a1 = *(const f32x4*)(arow + k0 + 4);
    f32x4 b0 = *(const f32x4*)(brow + k0);
    f32x4 b1 = *(const f32x4*)(brow + k0 + 4);
    acc = MFMA16(cvt8(a0, a1), cvt8(b0, b1), acc);
  }
#pragma unroll
  for (int r = 0; r < 4; ++r) {
    int m = m0 + g * 4 + r;
    hq[(size_t)m * (H_ * DK_) + n0 + r16] = (__bf16)acc[r];
  }
}

// ---------------------------------------------------------------------------
// K2: Aq[b, h, d] = (1/32) * sum_kk hq[b, h*64+kk] * Wk[h, kk, d]
// ---------------------------------------------------------------------------
__global__ __launch_bounds__(256) void k_aq(const __bf16* __restrict__ hq,
                                            const float* __restrict__ Wk,
                                            __bf16* __restrict__ Aq) {
  int tid = threadIdx.x, lane = tid & 63, wid = tid >> 6;
  int r16 = lane & 15, g = lane >> 4;
  int h = blockIdx.z;
  int n0 = (blockIdx.x * 4 + wid) * 16;
  int m0 = blockIdx.y * 16;
  const __bf16* arow = hq + (size_t)(m0 + r16) * (H_ * DK_) + h * DK_;
  const float* bcol = Wk + (size_t)h * DK_ * D_ + n0 + r16;  // + k*D_
  f32x4 acc = {0.f, 0.f, 0.f, 0.f};
#pragma unroll
  for (int ks = 0; ks < 2; ++ks) {
    int k0 = ks * 32 + g * 8;
    bf16x8 a = *(const bf16x8*)(arow + k0);
    f32x4 c0, c1;
#pragma unroll
    for (int j = 0; j < 4; ++j) c0[j] = bcol[(size_t)(k0 + j) * D_];
#pragma unroll
    for (int j = 0; j < 4; ++j) c1[j] = bcol[(size_t)(k0 + 4 + j) * D_];
    acc = MFMA16(a, cvt8(c0, c1), acc);
  }
#pragma unroll
  for (int r = 0; r < 4; ++r) {
    int m = m0 + g * 4 + r;
    Aq[(size_t)m * (H_ * D_) + (size_t)h * D_ + n0 + r16] = (__bf16)(acc[r] * 0.03125f);
  }
}

// ---------------------------------------------------------------------------
// K3a: scores[b, h, l] = Aq[b,h,:] . k[b,l,:]   (temp already folded into Aq)
// grid (4, 512): x = l-quarter (64 rows), y = b. block 256 (4 waves).
// 2048 blocks * 4 waves -> 100% occupancy capable (VGPR ~48, no LDS).
// ---------------------------------------------------------------------------
__global__ __launch_bounds__(256) void k_score(const float* __restrict__ kg,
                                               const __bf16* __restrict__ Aq,
                                               float* __restrict__ sc) {
  int tid = threadIdx.x, lane = tid & 63, wv = tid >> 6;
  int r16 = lane & 15, g = lane >> 4;
  int b = blockIdx.y;
  int l0 = blockIdx.x * 64 + wv * 16;
  const __bf16* AqB = Aq + (size_t)b * H_ * D_;
  const float*  kR  = kg + ((size_t)b * L_ + l0 + r16) * D_;
  f32x4 acc = {0.f, 0.f, 0.f, 0.f};
#pragma unroll 4
  for (int ks = 0; ks < D_ / 32; ++ks) {
    int k0 = ks * 32 + g * 8;
    bf16x8 a = *(const bf16x8*)(AqB + (size_t)r16 * D_ + k0);
    f32x4 b0 = *(const f32x4*)(kR + k0);
    f32x4 b1 = *(const f32x4*)(kR + k0 + 4);
    acc = MFMA16(a, cvt8(b0, b1), acc);
  }
#pragma unroll
  for (int r = 0; r < 4; ++r) {
    int h = g * 4 + r;
    sc[((size_t)b * H_ + h) * L_ + l0 + r16] = acc[r];
  }
}

// ---------------------------------------------------------------------------
// K3b: softmax prologue + cv[16,1024] = w[16,256] * v[256,1024] via MFMA.
// grid (4, 512): x = d-quarter (256 cols), y = b. block 256 (4 waves).
// Wave wv owns d-range [bx*256 + wv*64, +64) = 4 ntiles, full K=L=256 (8 ks).
// A-operand: w[h][l] bf16 in LDS (8.6KB), read as aligned ds_read_b128.
// B-operand: v via direct-global scalar dwords (4x64B segments/instr;
//            adjacent nt instrs complete each 128B line). No main-loop sync.
// ---------------------------------------------------------------------------
__global__ __launch_bounds__(256) void k_cv(const float* __restrict__ vg,
                                            const float* __restrict__ sc,
                                            __bf16* __restrict__ cv) {
  __shared__ __bf16 wA[H_][L_ + 8];  // w[h][l], row stride 528B (16B-mult)

  int tid = threadIdx.x, lane = tid & 63, wv = tid >> 6;
  int r16 = lane & 15, g = (lane >> 4) & 3;
  int b = blockIdx.y;

  // ---- softmax: wave wv handles head rows wv*4 .. wv*4+3
  const float* scB = sc + (size_t)b * H_ * L_;
#pragma unroll
  for (int rr = 0; rr < 4; ++rr) {
    int row = wv * 4 + rr;
    const float* srow = scB + (size_t)row * L_;
    float x0 = srow[lane], x1 = srow[lane + 64];
    float x2 = srow[lane + 128], x3 = srow[lane + 192];
    float m = fmaxf(fmaxf(x0, x1), fmaxf(x2, x3));
#pragma unroll
    for (int off = 32; off; off >>= 1) m = fmaxf(m, __shfl_xor(m, off));
    float e0 = __expf(x0 - m), e1 = __expf(x1 - m);
    float e2 = __expf(x2 - m), e3 = __expf(x3 - m);
    float s = e0 + e1 + e2 + e3;
#pragma unroll
    for (int off = 32; off; off >>= 1) s += __shfl_xor(s, off);
    float inv = 1.0f / s;
    wA[row][lane]       = (__bf16)(e0 * inv);
    wA[row][lane + 64]  = (__bf16)(e1 * inv);
    wA[row][lane + 128] = (__bf16)(e2 * inv);
    wA[row][lane + 192] = (__bf16)(e3 * inv);
  }
  __syncthreads();

  // ---- main: 4 ntiles x 8 k-slices of MFMA, v loaded direct from global.
  int dbase = blockIdx.x * 256 + wv * 64;
  const float* vB = vg + (size_t)b * L_ * D_ + dbase;
  f32x4 acc[4] = {{0.f,0.f,0.f,0.f},{0.f,0.f,0.f,0.f},
                  {0.f,0.f,0.f,0.f},{0.f,0.f,0.f,0.f}};
  for (int ks = 0; ks < 8; ++ks) {
    int l0 = ks * 32 + g * 8;
    bf16x8 a = *(const bf16x8*)(&wA[r16][l0]);
    const float* pv = vB + (size_t)l0 * D_ + r16;
#pragma unroll
    for (int nt = 0; nt < 4; ++nt) {
      const float* p = pv + nt * 16;
      f32x4 c0, c1;
#pragma unroll
      for (int j = 0; j < 4; ++j) c0[j] = p[(size_t)j * D_];
#pragma unroll
      for (int j = 0; j < 4; ++j) c1[j] = p[(size_t)(4 + j) * D_];
      acc[nt] = MFMA16(a, cvt8(c0, c1), acc[nt]);
    }
  }
  // D[m=h][n=d]: col = lane&15 (d offset), row = g*4 + r (head)
#pragma unroll
  for (int nt = 0; nt < 4; ++nt)
#pragma unroll
    for (int r = 0; r < 4; ++r)
      cv[((size_t)b * H_ + g * 4 + r) * D_ + dbase + nt * 16 + r16] = (__bf16)acc[nt][r];
}

// ---------------------------------------------------------------------------
// K4: ctx[b, h*64+vv] = sum_d cv[b,h,d] * Wv[h,vv,d]
// ---------------------------------------------------------------------------
__global__ __launch_bounds__(256) void k_ctx(const __bf16* __restrict__ cv,
                                             const float* __restrict__ Wv,
                                             __bf16* __restrict__ ctx) {
  int tid = threadIdx.x, lane = tid & 63, wid = tid >> 6;
  int r16 = lane & 15, g = lane >> 4;
  int h = blockIdx.z, m0 = blockIdx.y * 16, n0 = wid * 16;
  const __bf16* arow = cv + (size_t)(m0 + r16) * (H_ * D_) + (size_t)h * D_;
  const float* brow = Wv + (size_t)h * DV_ * D_ + (size_t)(n0 + r16) * D_;
  f32x4 acc = {0.f, 0.f, 0.f, 0.f};
  for (int ks = 0; ks < D_ / 32; ++ks) {
    int k0 = ks * 32 + g * 8;
    bf16x8 a = *(const bf16x8*)(arow + k0);
    f32x4 b0 = *(const f32x4*)(brow + k0);
    f32x4 b1 = *(const f32x4*)(brow + k0 + 4);
    acc = MFMA16(a, cvt8(b0, b1), acc);
  }
#pragma unroll
  for (int r = 0; r < 4; ++r) {
    int m = m0 + g * 4 + r;
    ctx[(size_t)m * (H_ * DV_) + h * DV_ + n0 + r16] = (__bf16)acc[r];
  }
}

// ---------------------------------------------------------------------------
// K5: outp[b,d] = sum_j ctx[b,j] * Wp[d,j] + q[b,d]
// ---------------------------------------------------------------------------
__global__ __launch_bounds__(256) void k_out(const __bf16* __restrict__ ctx,
                                             const float* __restrict__ Wp,
                                             const float* __restrict__ q,
                                             float* __restrict__ outp) {
  int tid = threadIdx.x, lane = tid & 63, wid = tid >> 6;
  int r16 = lane & 15, g = lane >> 4;
  int n0 = (blockIdx.x * 4 + wid) * 16;
  int m0 = blockIdx.y * 16;
  const __bf16* arow = ctx + (size_t)(m0 + r16) * D_;
  const float* brow = Wp + (size_t)(n0 + r16) * D_;
  f32x4 acc = {0.f, 0.f, 0.f, 0.f};
  for (int ks = 0; ks < D_ / 32; ++ks) {
    int k0 = ks * 32 + g * 8;
    bf16x8 a = *(const bf16x8*)(arow + k0);
    f32x4 b0 = *(const f32x4*)(brow + k0);
    f32x4 b1 = *(const f32x4*)(brow + k0 + 4);
    acc = MFMA16(a, cvt8(b0, b1), acc);
  }
#pragma unroll
  for (int r = 0; r < 4; ++r) {
    int m = m0 + g * 4 + r;
    outp[(size_t)m * D_ + n0 + r16] = acc[r] + q[(size_t)m * D_ + n0 + r16];
  }
}

// ---------------------------------------------------------------------------
// K6: LayerNorm, unbiased std (D-1), eps=1 added to STD.
// ---------------------------------------------------------------------------
__global__ __launch_bounds__(256) void k_ln(const float* __restrict__ xin,
                                            const float* __restrict__ scale,
                                            const float* __restrict__ offs,
                                            float* __restrict__ out) {
  __shared__ float red[4];
  int b = blockIdx.x, tid = threadIdx.x;
  const float* row = xin + (size_t)b * D_;
  f32x4 x = *(const f32x4*)(row + tid * 4);
  float s = x[0] + x[1] + x[2] + x[3];
#pragma unroll
  for (int off = 32; off; off >>= 1) s += __shfl_xor(s, off);
  if ((tid & 63) == 0) red[tid >> 6] = s;
  __syncthreads();
  float mean = (red[0] + red[1] + red[2] + red[3]) * (1.0f / D_);
  __syncthreads();  // before reusing red
  float vs = 0.f;
#pragma unroll
  for (int j = 0; j < 4; ++j) { float d = x[j] - mean; vs += d * d; }
#pragma unroll
  for (int off = 32; off; off >>= 1) vs += __shfl_xor(vs, off);
  if ((tid & 63) == 0) red[tid >> 6] = vs;
  __syncthreads();
  float var = (red[0] + red[1] + red[2] + red[3]) * (1.0f / (D_ - 1));
  float inv = 1.0f / (sqrtf(var) + 1.0f);
  f32x4 sc = *(const f32x4*)(scale + tid * 4);
  f32x4 of = *(const f32x4*)(offs + tid * 4);
  f32x4 o;
#pragma unroll
  for (int j = 0; j < 4; ++j) o[j] = sc[j] * (x[j] - mean) * inv + of[j];
  *(f32x4*)(out + (size_t)b * D_ + tid * 4) = o;
}

// ---------------------------------------------------------------------------
extern "C" void kernel_launch(void* const* d_in, const int* in_sizes, int n_in,
                              void* d_out, int out_size, void* d_ws, size_t ws_size,
                              hipStream_t stream) {
  const float* q     = (const float*)d_in[0];
  const float* k     = (const float*)d_in[1];
  const float* v     = (const float*)d_in[2];
  const float* Wq    = (const float*)d_in[3];
  const float* Wk    = (const float*)d_in[4];
  const float* Wv    = (const float*)d_in[5];
  const float* Wp    = (const float*)d_in[6];
  const float* scale = (const float*)d_in[7];
  const float* offs  = (const float*)d_in[8];
  float* out = (float*)d_out;

  // Workspace layout:
  char* ws = (char*)d_ws;
  __bf16* hq   = (__bf16*)(ws);                          // 1 MB
  __bf16* Aq   = (__bf16*)(ws + (size_t)1  * (1 << 20)); // 16 MB
  float*  scr  = (float*) (ws + (size_t)17 * (1 << 20)); // 8 MB  (raw scores)
  __bf16* cv   = (__bf16*)(ws + (size_t)25 * (1 << 20)); // 16 MB
  __bf16* ctx  = (__bf16*)(ws + (size_t)41 * (1 << 20)); // 1 MB
  float*  outp = (float*) (ws + (size_t)42 * (1 << 20)); // 2 MB

  k_hq   <<<dim3(16, 32),     256, 0, stream>>>(q, Wq, hq);
  k_aq   <<<dim3(16, 32, 16), 256, 0, stream>>>(hq, Wk, Aq);
  k_score<<<dim3(4, 512),     256, 0, stream>>>(k, Aq, scr);
  k_cv   <<<dim3(4, 512),     256, 0, stream>>>(v, scr, cv);
  k_ctx  <<<dim3(1, 32, 16),  256, 0, stream>>>(cv, Wv, ctx);
  k_out  <<<dim3(16, 32),     256, 0, stream>>>(ctx, Wp, q, outp);
  k_ln   <<<dim3(512),        256, 0, stream>>>(outp, scale, offs, out);
}

// Round 6
// 312.860 us; speedup vs baseline: 1.2010x; 1.0000x over previous
//
#include <hip/hip_runtime.h>

// Problem constants
#define B_ 512
#define L_ 256
#define D_ 1024
#define H_ 16
#define DK_ 64
#define DV_ 64
// TEMP = sqrt(1024) = 32 exactly (folded into Aq in k_proj)

typedef float f32x4 __attribute__((ext_vector_type(4)));
typedef float f32x2 __attribute__((ext_vector_type(2)));
typedef __bf16 bf16x8 __attribute__((ext_vector_type(8)));
typedef __bf16 bf16x2 __attribute__((ext_vector_type(2)));

#define MFMA16(a, b, c) __builtin_amdgcn_mfma_f32_16x16x32_bf16((a), (b), (c), 0, 0, 0)

__device__ inline bf16x8 cvt8(f32x4 a, f32x4 b) {
  bf16x8 r;
  r[0] = (__bf16)a[0]; r[1] = (__bf16)a[1]; r[2] = (__bf16)a[2]; r[3] = (__bf16)a[3];
  r[4] = (__bf16)b[0]; r[5] = (__bf16)b[1]; r[6] = (__bf16)b[2]; r[7] = (__bf16)b[3];
  return r;
}

// ---------------------------------------------------------------------------
// K1: fused q-proj + Wk-proj.  grid (32 m-tiles, 16 h), block 256 (4 waves).
//   Step 1: hq_t[16,64] = q[m0:16,:] . Wq[h*64:+64,:]^T   (K=1024) -> LDS bf16
//   Step 2: Aq[m0:16, h, :] = (1/32) * hq_t . Wk[h]       (K=64)
// ---------------------------------------------------------------------------
__global__ __launch_bounds__(256) void k_proj(const float* __restrict__ q,
                                              const float* __restrict__ Wq,
                                              const float* __restrict__ Wk,
                                              __bf16* __restrict__ Aq) {
  __shared__ __bf16 hq_lds[16][80];  // row stride 160B (16B-mult)
  int tid = threadIdx.x, lane = tid & 63, wid = tid >> 6;
  int r16 = lane & 15, g = lane >> 4;
  int m0 = blockIdx.x * 16, h = blockIdx.y;

  // ---- Step 1: wave wid computes kk-ntile wid*16
  {
    const float* arow = q  + (size_t)(m0 + r16) * D_;
    const float* brow = Wq + (size_t)(h * DK_ + wid * 16 + r16) * D_;
    f32x4 acc = {0.f, 0.f, 0.f, 0.f};
    for (int ks = 0; ks < D_ / 32; ++ks) {
      int k0 = ks * 32 + g * 8;
      f32x4 a0 = *(const f32x4*)(arow + k0);
      f32x4 a1 = *(const f32x4*)(arow + k0 + 4);
      f32x4 b0 = *(const f32x4*)(brow + k0);
      f32x4 b1 = *(const f32x4*)(brow + k0 + 4);
      acc = MFMA16(cvt8(a0, a1), cvt8(b0, b1), acc);
    }
#pragma unroll
    for (int r = 0; r < 4; ++r)
      hq_lds[g * 4 + r][wid * 16 + r16] = (__bf16)acc[r];
  }
  __syncthreads();

  // ---- Step 2: wave wid owns d-cols [wid*256, +256) = 16 ntiles
  const float* bcolBase = Wk + (size_t)h * DK_ * D_;
  for (int nt = 0; nt < 16; ++nt) {
    int n0 = wid * 256 + nt * 16;
    const float* bcol = bcolBase + n0 + r16;  // + k*D_
    f32x4 acc = {0.f, 0.f, 0.f, 0.f};
#pragma unroll
    for (int ks = 0; ks < 2; ++ks) {
      int k0 = ks * 32 + g * 8;
      bf16x8 a = *(const bf16x8*)(&hq_lds[r16][k0]);
      f32x4 c0, c1;
#pragma unroll
      for (int j = 0; j < 4; ++j) c0[j] = bcol[(size_t)(k0 + j) * D_];
#pragma unroll
      for (int j = 0; j < 4; ++j) c1[j] = bcol[(size_t)(k0 + 4 + j) * D_];
      acc = MFMA16(a, cvt8(c0, c1), acc);
    }
#pragma unroll
    for (int r = 0; r < 4; ++r) {
      int m = m0 + g * 4 + r;
      Aq[(size_t)m * (H_ * D_) + (size_t)h * D_ + n0 + r16] = (__bf16)(acc[r] * 0.03125f);
    }
  }
}

// ---------------------------------------------------------------------------
// K2: scores[b, h, l] = Aq[b,h,:] . k[b,l,:]   (temp already folded into Aq)
// 1-D grid 2048, XCD-swizzled so each b's 4 blocks share one XCD's L2
// (Aq[b] 32KB then L2-hit for 3 of 4 blocks). block 256 (4 waves).
// ---------------------------------------------------------------------------
__global__ __launch_bounds__(256) void k_score(const float* __restrict__ kg,
                                               const __bf16* __restrict__ Aq,
                                               float* __restrict__ sc) {
  int tid = threadIdx.x, lane = tid & 63, wv = tid >> 6;
  int r16 = lane & 15, g = lane >> 4;
  // bijective XCD swizzle: 2048 % 8 == 0
  int wg = blockIdx.x;
  int vid = (wg & 7) * 256 + (wg >> 3);
  int b = vid >> 2;             // 0..511
  int lq = vid & 3;             // l-quarter
  int l0 = lq * 64 + wv * 16;
  const __bf16* AqB = Aq + (size_t)b * H_ * D_;
  const float*  kR  = kg + ((size_t)b * L_ + l0 + r16) * D_;
  f32x4 acc = {0.f, 0.f, 0.f, 0.f};
#pragma unroll 4
  for (int ks = 0; ks < D_ / 32; ++ks) {
    int k0 = ks * 32 + g * 8;
    bf16x8 a = *(const bf16x8*)(AqB + (size_t)r16 * D_ + k0);
    f32x4 b0 = *(const f32x4*)(kR + k0);
    f32x4 b1 = *(const f32x4*)(kR + k0 + 4);
    acc = MFMA16(a, cvt8(b0, b1), acc);
  }
#pragma unroll
  for (int r = 0; r < 4; ++r) {
    int h = g * 4 + r;
    sc[((size_t)b * H_ + h) * L_ + l0 + r16] = acc[r];
  }
}

// ---------------------------------------------------------------------------
// K3: softmax prologue + cv[16,1024] = w[16,256] * v[256,1024] via MFMA.
// 1-D grid 2048, XCD-swizzled (sc[b] shared by 4 blocks). block 256 (4 waves).
// Wave wv owns d-range [dq*256 + wv*64, +64) = 4 ntiles, full K=L=256.
// ---------------------------------------------------------------------------
__global__ __launch_bounds__(256) void k_cv(const float* __restrict__ vg,
                                            const float* __restrict__ sc,
                                            __bf16* __restrict__ cv) {
  __shared__ __bf16 wA[H_][L_ + 8];  // w[h][l], row stride 528B (16B-mult)

  int tid = threadIdx.x, lane = tid & 63, wv = tid >> 6;
  int r16 = lane & 15, g = (lane >> 4) & 3;
  int wg = blockIdx.x;
  int vid = (wg & 7) * 256 + (wg >> 3);
  int b = vid >> 2;
  int dq = vid & 3;

  // ---- softmax: wave wv handles head rows wv*4 .. wv*4+3
  const float* scB = sc + (size_t)b * H_ * L_;
#pragma unroll
  for (int rr = 0; rr < 4; ++rr) {
    int row = wv * 4 + rr;
    const float* srow = scB + (size_t)row * L_;
    float x0 = srow[lane], x1 = srow[lane + 64];
    float x2 = srow[lane + 128], x3 = srow[lane + 192];
    float m = fmaxf(fmaxf(x0, x1), fmaxf(x2, x3));
#pragma unroll
    for (int off = 32; off; off >>= 1) m = fmaxf(m, __shfl_xor(m, off));
    float e0 = __expf(x0 - m), e1 = __expf(x1 - m);
    float e2 = __expf(x2 - m), e3 = __expf(x3 - m);
    float s = e0 + e1 + e2 + e3;
#pragma unroll
    for (int off = 32; off; off >>= 1) s += __shfl_xor(s, off);
    float inv = 1.0f / s;
    wA[row][lane]       = (__bf16)(e0 * inv);
    wA[row][lane + 64]  = (__bf16)(e1 * inv);
    wA[row][lane + 128] = (__bf16)(e2 * inv);
    wA[row][lane + 192] = (__bf16)(e3 * inv);
  }
  __syncthreads();

  // ---- main: 4 ntiles x 8 k-slices of MFMA, v loaded direct from global.
  int dbase = dq * 256 + wv * 64;
  const float* vB = vg + (size_t)b * L_ * D_ + dbase;
  f32x4 acc[4] = {{0.f,0.f,0.f,0.f},{0.f,0.f,0.f,0.f},
                  {0.f,0.f,0.f,0.f},{0.f,0.f,0.f,0.f}};
#pragma unroll 2
  for (int ks = 0; ks < 8; ++ks) {
    int l0 = ks * 32 + g * 8;
    bf16x8 a = *(const bf16x8*)(&wA[r16][l0]);
    const float* pv = vB + (size_t)l0 * D_ + r16;
#pragma unroll
    for (int nt = 0; nt < 4; ++nt) {
      const float* p = pv + nt * 16;
      f32x4 c0, c1;
#pragma unroll
      for (int j = 0; j < 4; ++j) c0[j] = p[(size_t)j * D_];
#pragma unroll
      for (int j = 0; j < 4; ++j) c1[j] = p[(size_t)(4 + j) * D_];
      acc[nt] = MFMA16(a, cvt8(c0, c1), acc[nt]);
    }
  }
#pragma unroll
  for (int nt = 0; nt < 4; ++nt)
#pragma unroll
    for (int r = 0; r < 4; ++r)
      cv[((size_t)b * H_ + g * 4 + r) * D_ + dbase + nt * 16 + r16] = (__bf16)acc[nt][r];
}

// ---------------------------------------------------------------------------
// K4: ctx[b, h*64+vv] = sum_d cv[b,h,d] * Wv[h,vv,d]
// ---------------------------------------------------------------------------
__global__ __launch_bounds__(256) void k_ctx(const __bf16* __restrict__ cv,
                                             const float* __restrict__ Wv,
                                             __bf16* __restrict__ ctx) {
  int tid = threadIdx.x, lane = tid & 63, wid = tid >> 6;
  int r16 = lane & 15, g = lane >> 4;
  int h = blockIdx.z, m0 = blockIdx.y * 16, n0 = wid * 16;
  const __bf16* arow = cv + (size_t)(m0 + r16) * (H_ * D_) + (size_t)h * D_;
  const float* brow = Wv + (size_t)h * DV_ * D_ + (size_t)(n0 + r16) * D_;
  f32x4 acc = {0.f, 0.f, 0.f, 0.f};
  for (int ks = 0; ks < D_ / 32; ++ks) {
    int k0 = ks * 32 + g * 8;
    bf16x8 a = *(const bf16x8*)(arow + k0);
    f32x4 b0 = *(const f32x4*)(brow + k0);
    f32x4 b1 = *(const f32x4*)(brow + k0 + 4);
    acc = MFMA16(a, cvt8(b0, b1), acc);
  }
#pragma unroll
  for (int r = 0; r < 4; ++r) {
    int m = m0 + g * 4 + r;
    ctx[(size_t)m * (H_ * DV_) + h * DV_ + n0 + r16] = (__bf16)acc[r];
  }
}

// ---------------------------------------------------------------------------
// K5: outp[b,d] = sum_j ctx[b,j] * Wp[d,j] + q[b,d]
// ---------------------------------------------------------------------------
__global__ __launch_bounds__(256) void k_out(const __bf16* __restrict__ ctx,
                                             const float* __restrict__ Wp,
                                             const float* __restrict__ q,
                                             float* __restrict__ outp) {
  int tid = threadIdx.x, lane = tid & 63, wid = tid >> 6;
  int r16 = lane & 15, g = lane >> 4;
  int n0 = (blockIdx.x * 4 + wid) * 16;
  int m0 = blockIdx.y * 16;
  const __bf16* arow = ctx + (size_t)(m0 + r16) * D_;
  const float* brow = Wp + (size_t)(n0 + r16) * D_;
  f32x4 acc = {0.f, 0.f, 0.f, 0.f};
  for (int ks = 0; ks < D_ / 32; ++ks) {
    int k0 = ks * 32 + g * 8;
    bf16x8 a = *(const bf16x8*)(arow + k0);
    f32x4 b0 = *(const f32x4*)(brow + k0);
    f32x4 b1 = *(const f32x4*)(brow + k0 + 4);
    acc = MFMA16(a, cvt8(b0, b1), acc);
  }
#pragma unroll
  for (int r = 0; r < 4; ++r) {
    int m = m0 + g * 4 + r;
    outp[(size_t)m * D_ + n0 + r16] = acc[r] + q[(size_t)m * D_ + n0 + r16];
  }
}

// ---------------------------------------------------------------------------
// K6: LayerNorm, unbiased std (D-1), eps=1 added to STD.
// ---------------------------------------------------------------------------
__global__ __launch_bounds__(256) void k_ln(const float* __restrict__ xin,
                                            const float* __restrict__ scale,
                                            const float* __restrict__ offs,
                                            float* __restrict__ out) {
  __shared__ float red[4];
  int b = blockIdx.x, tid = threadIdx.x;
  const float* row = xin + (size_t)b * D_;
  f32x4 x = *(const f32x4*)(row + tid * 4);
  float s = x[0] + x[1] + x[2] + x[3];
#pragma unroll
  for (int off = 32; off; off >>= 1) s += __shfl_xor(s, off);
  if ((tid & 63) == 0) red[tid >> 6] = s;
  __syncthreads();
  float mean = (red[0] + red[1] + red[2] + red[3]) * (1.0f / D_);
  __syncthreads();  // before reusing red
  float vs = 0.f;
#pragma unroll
  for (int j = 0; j < 4; ++j) { float d = x[j] - mean; vs += d * d; }
#pragma unroll
  for (int off = 32; off; off >>= 1) vs += __shfl_xor(vs, off);
  if ((tid & 63) == 0) red[tid >> 6] = vs;
  __syncthreads();
  float var = (red[0] + red[1] + red[2] + red[3]) * (1.0f / (D_ - 1));
  float inv = 1.0f / (sqrtf(var) + 1.0f);
  f32x4 sc = *(const f32x4*)(scale + tid * 4);
  f32x4 of = *(const f32x4*)(offs + tid * 4);
  f32x4 o;
#pragma unroll
  for (int j = 0; j < 4; ++j) o[j] = sc[j] * (x[j] - mean) * inv + of[j];
  *(f32x4*)(out + (size_t)b * D_ + tid * 4) = o;
}

// ---------------------------------------------------------------------------
extern "C" void kernel_launch(void* const* d_in, const int* in_sizes, int n_in,
                              void* d_out, int out_size, void* d_ws, size_t ws_size,
                              hipStream_t stream) {
  const float* q     = (const float*)d_in[0];
  const float* k     = (const float*)d_in[1];
  const float* v     = (const float*)d_in[2];
  const float* Wq    = (const float*)d_in[3];
  const float* Wk    = (const float*)d_in[4];
  const float* Wv    = (const float*)d_in[5];
  const float* Wp    = (const float*)d_in[6];
  const float* scale = (const float*)d_in[7];
  const float* offs  = (const float*)d_in[8];
  float* out = (float*)d_out;

  // Workspace layout:
  char* ws = (char*)d_ws;
  __bf16* Aq   = (__bf16*)(ws);                          // 16 MB
  float*  scr  = (float*) (ws + (size_t)16 * (1 << 20)); // 8 MB  (raw scores)
  __bf16* cv   = (__bf16*)(ws + (size_t)24 * (1 << 20)); // 16 MB
  __bf16* ctx  = (__bf16*)(ws + (size_t)40 * (1 << 20)); // 1 MB
  float*  outp = (float*) (ws + (size_t)41 * (1 << 20)); // 2 MB

  k_proj <<<dim3(32, 16),     256, 0, stream>>>(q, Wq, Wk, Aq);
  k_score<<<dim3(2048),       256, 0, stream>>>(k, Aq, scr);
  k_cv   <<<dim3(2048),       256, 0, stream>>>(v, scr, cv);
  k_ctx  <<<dim3(1, 32, 16),  256, 0, stream>>>(cv, Wv, ctx);
  k_out  <<<dim3(16, 32),     256, 0, stream>>>(ctx, Wp, q, outp);
  k_ln   <<<dim3(512),        256, 0, stream>>>(outp, scale, offs, out);
}